// Round 3
// baseline (318.492 us; speedup 1.0000x reference)
//
#include <hip/hip_runtime.h>

// Fused ResidualTokenAdapter, occupancy-first formulation.
// LN folded into down-proj (h_n = rs*(dot(x_raw,dw'_n) - mu*sdw_n) + db'_n), so the
// down-GEMM consumes RAW x and stats are a post-hoc scalar correction.
// Round-2 lesson: one wave per 16 rows = 2048 waves = 19.7% occupancy -> latency-bound
// at 2.3 TB/s. This version splits K (down) and N (up) across the block's 4 waves:
//   block = 16 rows; wave w: down-partial over K in [w*256,(w+1)*256), then after a
//   barrier reduces n-block [w*16,(w+1)*16) + GELU -> g, then up-GEMM for cols
//   [w*256,(w+1)*256). Grid = 2048 blocks = 8192 waves (4x round 2).
// LDS: part[4][64][20] fp32 (20.0 KB, stride 20 keeps 16B align + bank spread)
//      + stats 512 B + g[16][72] bf16 (2.3 KB) = 23.3 KB -> 6 blocks/CU.

#define HDIM 1024
#define BDIM 64

using s16x8 = __attribute__((ext_vector_type(8))) short;
using f32x4 = __attribute__((ext_vector_type(4))) float;

__device__ float g_wstat[128];   // [0:64) sdw, [64:128) db2 — static, not workspace

__device__ __forceinline__ short f2bf(float f) {
  unsigned u = __builtin_bit_cast(unsigned, f);
  u += 0x7fffu + ((u >> 16) & 1u);          // round-to-nearest-even
  return (short)(u >> 16);
}
__device__ __forceinline__ float bf2f(short s) {
  unsigned u = ((unsigned)(unsigned short)s) << 16;
  return __builtin_bit_cast(float, u);
}

// prep: blocks 0..63 convert weights to bf16 (gamma folded into dw);
// block 64 computes sdw[64] (bf16-rounded, matching GEMM operand) and db2[64].
extern "C" __global__ void prep_weights(const float* __restrict__ dw,
                                        const float* __restrict__ uw,
                                        const float* __restrict__ nw,
                                        const float* __restrict__ nb,
                                        const float* __restrict__ db,
                                        short* __restrict__ wsbf) {
  const int b = blockIdx.x;
  if (b < 64) {
    int tid = b * 256 + threadIdx.x;                 // 0..16383
    if (tid < 8192) {                                // dw' = gamma * dw
      int off = tid * 8;
      int k = off & (HDIM - 1);
      f32x4 v0 = *(const f32x4*)(dw + off);
      f32x4 v1 = *(const f32x4*)(dw + off + 4);
      f32x4 g0 = *(const f32x4*)(nw + k);
      f32x4 g1 = *(const f32x4*)(nw + k + 4);
      s16x8 o;
#pragma unroll
      for (int j = 0; j < 4; ++j) {
        o[j]     = f2bf(v0[j] * g0[j]);
        o[j + 4] = f2bf(v1[j] * g1[j]);
      }
      *(s16x8*)(wsbf + tid * 8) = o;
    } else {                                         // uw unchanged
      int off = (tid - 8192) * 8;
      f32x4 v0 = *(const f32x4*)(uw + off);
      f32x4 v1 = *(const f32x4*)(uw + off + 4);
      s16x8 o;
#pragma unroll
      for (int j = 0; j < 4; ++j) { o[j] = f2bf(v0[j]); o[j + 4] = f2bf(v1[j]); }
      *(s16x8*)(wsbf + tid * 8) = o;
    }
  } else {
    // stats: 4 threads per n, each sums 256 k's
    const int t = threadIdx.x;
    const int n = t >> 2, p = t & 3;
    const float* dwn = dw + n * HDIM;
    float s1 = 0.f, s2 = 0.f;
    for (int j = 0; j < 32; ++j) {
      int k = p * 256 + j * 8;
      f32x4 v0 = *(const f32x4*)(dwn + k);
      f32x4 v1 = *(const f32x4*)(dwn + k + 4);
      f32x4 g0 = *(const f32x4*)(nw + k);
      f32x4 g1 = *(const f32x4*)(nw + k + 4);
      f32x4 b0 = *(const f32x4*)(nb + k);
      f32x4 b1 = *(const f32x4*)(nb + k + 4);
#pragma unroll
      for (int jj = 0; jj < 4; ++jj) {
        s1 += bf2f(f2bf(v0[jj] * g0[jj])) + bf2f(f2bf(v1[jj] * g1[jj]));
        s2 += v0[jj] * b0[jj] + v1[jj] * b1[jj];
      }
    }
    s1 += __shfl_xor(s1, 1); s1 += __shfl_xor(s1, 2);
    s2 += __shfl_xor(s2, 1); s2 += __shfl_xor(s2, 2);
    if (p == 0) {
      g_wstat[n]      = s1;            // sdw
      g_wstat[64 + n] = db[n] + s2;    // db2
    }
  }
}

extern "C" __global__ __launch_bounds__(256, 6)
void adapter_fused(const float* __restrict__ x,
                   const float* __restrict__ ub,
                   const short* __restrict__ dwb,
                   const short* __restrict__ uwb,
                   float* __restrict__ out)
{
  // part[w][n][row] : wave w's partial D for n=0..63, rows 0..15.
  // row-stride 20 floats = 80 B: keeps q*4 element (16 B) alignment for b128,
  // odd-ish bank spread (20 mod 32) across c.
  __shared__ __align__(16) float part[4][64][20];    // 20480 B
  __shared__ float ssum[4][16];                      // 256 B
  __shared__ float sssq[4][16];                      // 256 B
  __shared__ __align__(16) short g[16][72];          // 2304 B  (144 B row = 16B mult)

  const int t    = threadIdx.x;
  const int w    = t >> 6;            // wave 0..3
  const int lane = t & 63;
  const int q    = lane >> 4;
  const int c    = lane & 15;
  const size_t rowbase = (size_t)blockIdx.x * 16;

  // ---- phase 1: partial down-GEMM over K-quarter [w*256,(w+1)*256) ----
  // A fragment-order from global: lane(q,c) reads row c, cols w*256+ks*32+q*8
  // (4 q-lanes cover each 128 B segment exactly once).
  const float* pA  = x   + (rowbase + c) * HDIM + w * 256 + q * 8;
  const short* pB0 = dwb + (size_t)( 0 + c) * HDIM + w * 256 + q * 8;
  const short* pB1 = dwb + (size_t)(16 + c) * HDIM + w * 256 + q * 8;
  const short* pB2 = dwb + (size_t)(32 + c) * HDIM + w * 256 + q * 8;
  const short* pB3 = dwb + (size_t)(48 + c) * HDIM + w * 256 + q * 8;

  f32x4 acc0 = {0.f,0.f,0.f,0.f}, acc1 = acc0, acc2 = acc0, acc3 = acc0;
  float sum = 0.f, ssq = 0.f;

#pragma unroll
  for (int ks = 0; ks < 8; ++ks) {
    f32x4 v0 = *(const f32x4*)(pA + ks * 32);
    f32x4 v1 = *(const f32x4*)(pA + ks * 32 + 4);
    s16x8 b0 = *(const s16x8*)(pB0 + ks * 32);
    s16x8 b1 = *(const s16x8*)(pB1 + ks * 32);
    s16x8 b2 = *(const s16x8*)(pB2 + ks * 32);
    s16x8 b3 = *(const s16x8*)(pB3 + ks * 32);
    s16x8 a;
#pragma unroll
    for (int j = 0; j < 4; ++j) {
      float f0 = v0[j]; sum += f0; ssq += f0 * f0; a[j]     = f2bf(f0);
      float f1 = v1[j]; sum += f1; ssq += f1 * f1; a[j + 4] = f2bf(f1);
    }
    acc0 = __builtin_amdgcn_mfma_f32_16x16x32_bf16(a, b0, acc0, 0, 0, 0);
    acc1 = __builtin_amdgcn_mfma_f32_16x16x32_bf16(a, b1, acc1, 0, 0, 0);
    acc2 = __builtin_amdgcn_mfma_f32_16x16x32_bf16(a, b2, acc2, 0, 0, 0);
    acc3 = __builtin_amdgcn_mfma_f32_16x16x32_bf16(a, b3, acc3, 0, 0, 0);
  }

  // partial stats: lanes {q*16+c} jointly saw 256 elems of row c in this K-quarter
  sum += __shfl_xor(sum, 16); sum += __shfl_xor(sum, 32);
  ssq += __shfl_xor(ssq, 16); ssq += __shfl_xor(ssq, 32);
  if (lane < 16) { ssum[w][c] = sum; sssq[w][c] = ssq; }

  // partial acc -> LDS: acc_j[i] is D[row=q*4+i][n=j*16+c]; part[w][n][row] makes
  // the 4 components contiguous -> one b128 per j.
  *(f32x4*)&part[w][ 0 + c][q * 4] = acc0;
  *(f32x4*)&part[w][16 + c][q * 4] = acc1;
  *(f32x4*)&part[w][32 + c][q * 4] = acc2;
  *(f32x4*)&part[w][48 + c][q * 4] = acc3;

  __syncthreads();

  // ---- phase 2: wave w reduces n-block [w*16,(w+1)*16), GELU, write g ----
  {
    const int n = w * 16 + c;
    f32x4 p0 = *(const f32x4*)&part[0][n][q * 4];
    f32x4 p1 = *(const f32x4*)&part[1][n][q * 4];
    f32x4 p2 = *(const f32x4*)&part[2][n][q * 4];
    f32x4 p3 = *(const f32x4*)&part[3][n][q * 4];
    f32x4 h4 = (p0 + p1) + (p2 + p3);               // rows q*4+0..3, col n

    const int rr = lane & 15;                       // stats for row rr (broadcast reads)
    float sT = (ssum[0][rr] + ssum[1][rr]) + (ssum[2][rr] + ssum[3][rr]);
    float qT = (sssq[0][rr] + sssq[1][rr]) + (sssq[2][rr] + sssq[3][rr]);
    const float muL = sT * (1.0f / HDIM);
    const float rsL = rsqrtf(qT * (1.0f / HDIM) - muL * muL + 1e-5f);

    const float sdw = g_wstat[n];
    const float dbv = g_wstat[64 + n];
#pragma unroll
    for (int i = 0; i < 4; ++i) {
      const float m  = __shfl(muL, q * 4 + i);
      const float rv = __shfl(rsL, q * 4 + i);
      float h = rv * (h4[i] - m * sdw) + dbv;
      g[q * 4 + i][n] = f2bf(0.5f * h * (1.0f + erff(h * 0.70710678118654752f)));
    }
  }
  __syncthreads();

  // ---- phase 3: up-GEMM, wave w owns cols [w*256,(w+1)*256) ----
  const s16x8 a0 = *(const s16x8*)&g[c][q * 8];       // k = 0..31
  const s16x8 a1 = *(const s16x8*)&g[c][32 + q * 8];  // k = 32..63

  const float* xr0 = x + (rowbase + q * 4 + 0) * HDIM + w * 256 + c;
  const float* xr1 = x + (rowbase + q * 4 + 1) * HDIM + w * 256 + c;
  const float* xr2 = x + (rowbase + q * 4 + 2) * HDIM + w * 256 + c;
  const float* xr3 = x + (rowbase + q * 4 + 3) * HDIM + w * 256 + c;
  float* or0 = out + (rowbase + q * 4 + 0) * HDIM + w * 256 + c;
  float* or1 = out + (rowbase + q * 4 + 1) * HDIM + w * 256 + c;
  float* or2 = out + (rowbase + q * 4 + 2) * HDIM + w * 256 + c;
  float* or3 = out + (rowbase + q * 4 + 3) * HDIM + w * 256 + c;
  const short* pu = uwb + (size_t)(w * 256 + c) * BDIM + q * 8;
  const float* pub = ub + w * 256 + c;

#pragma unroll 4
  for (int nt = 0; nt < 16; ++nt) {
    const short* uwrow = pu + (size_t)nt * 16 * BDIM;
    s16x8 b0 = *(const s16x8*)(uwrow);
    s16x8 b1 = *(const s16x8*)(uwrow + 32);
    f32x4 o4 = {0.f,0.f,0.f,0.f};
    o4 = __builtin_amdgcn_mfma_f32_16x16x32_bf16(a0, b0, o4, 0, 0, 0);
    o4 = __builtin_amdgcn_mfma_f32_16x16x32_bf16(a1, b1, o4, 0, 0, 0);
    const float ubv = pub[nt * 16];
    const int co = nt * 16;                            // imm-offset loads/stores
    or0[co] = o4[0] + ubv + xr0[co];                   // residual from fp32 x (L3-hot)
    or1[co] = o4[1] + ubv + xr1[co];
    or2[co] = o4[2] + ubv + xr2[co];
    or3[co] = o4[3] + ubv + xr3[co];
  }
}

extern "C" void kernel_launch(void* const* d_in, const int* in_sizes, int n_in,
                              void* d_out, int out_size, void* d_ws, size_t ws_size,
                              hipStream_t stream) {
  const float* x  = (const float*)d_in[0];
  const float* nw = (const float*)d_in[1];
  const float* nb = (const float*)d_in[2];
  const float* dw = (const float*)d_in[3];
  const float* db = (const float*)d_in[4];
  const float* uw = (const float*)d_in[5];
  const float* ub = (const float*)d_in[6];
  float* out = (float*)d_out;

  short* wsbf = (short*)d_ws;                         // exactly 256 KB bf16 weights
  prep_weights<<<65, 256, 0, stream>>>(dw, uw, nw, nb, db, wsbf);

  const int rows = in_sizes[0] / HDIM;                // 32768
  const int grid = rows / 16;                         // 2048 blocks x 4 waves
  adapter_fused<<<grid, 256, 0, stream>>>(x, ub, wsbf, wsbf + 65536, out);
}

// Round 4
// 299.452 us; speedup vs baseline: 1.0636x; 1.0636x over previous
//
#include <hip/hip_runtime.h>

// Fused ResidualTokenAdapter v4: coalesced + deep-MLP ingest.
// LN folded into down-proj (h_n = rs*(dot(x_raw,dw'_n) - mu*sdw_n) + db'_n).
// Round-3 lesson: occupancy 51% did NOT help; all variants stuck at ~2.1 TB/s with
// shallow per-wave in-flight bytes (VGPR=40, JIT-scheduled loads) and 16-line
// scattered fragment loads. v4: phase 1 loads the 16x1024 x-tile fully coalesced
// (f32x4, 8 lanes/line) with EXPLICIT 16-deep register staging (16 KB in flight
// per wave), computes row stats, stores bf16 to a swizzled LDS tile; down-GEMM
// reads A from LDS (conflict-free via 16B-slot XOR swizzle); N-split by wave
// (no reduce buffer). LDS 34.7 KB -> 4 blocks/CU. 2 barriers.

#define HDIM 1024
#define BDIM 64

using s16x8 = __attribute__((ext_vector_type(8))) short;
using s16x4 = __attribute__((ext_vector_type(4))) short;
using f32x4 = __attribute__((ext_vector_type(4))) float;

__device__ float g_wstat[128];   // [0:64) sdw, [64:128) db2

__device__ __forceinline__ short f2bf(float f) {
  unsigned u = __builtin_bit_cast(unsigned, f);
  u += 0x7fffu + ((u >> 16) & 1u);          // round-to-nearest-even
  return (short)(u >> 16);
}
__device__ __forceinline__ float bf2f(short s) {
  unsigned u = ((unsigned)(unsigned short)s) << 16;
  return __builtin_bit_cast(float, u);
}

// prep: blocks 0..63 convert weights to bf16 (gamma folded into dw);
// block 64 computes sdw[64] (bf16-rounded, matching GEMM operand) and db2[64].
extern "C" __global__ void prep_weights(const float* __restrict__ dw,
                                        const float* __restrict__ uw,
                                        const float* __restrict__ nw,
                                        const float* __restrict__ nb,
                                        const float* __restrict__ db,
                                        short* __restrict__ wsbf) {
  const int b = blockIdx.x;
  if (b < 64) {
    int tid = b * 256 + threadIdx.x;                 // 0..16383
    if (tid < 8192) {                                // dw' = gamma * dw
      int off = tid * 8;
      int k = off & (HDIM - 1);
      f32x4 v0 = *(const f32x4*)(dw + off);
      f32x4 v1 = *(const f32x4*)(dw + off + 4);
      f32x4 g0 = *(const f32x4*)(nw + k);
      f32x4 g1 = *(const f32x4*)(nw + k + 4);
      s16x8 o;
#pragma unroll
      for (int j = 0; j < 4; ++j) {
        o[j]     = f2bf(v0[j] * g0[j]);
        o[j + 4] = f2bf(v1[j] * g1[j]);
      }
      *(s16x8*)(wsbf + tid * 8) = o;
    } else {                                         // uw unchanged
      int off = (tid - 8192) * 8;
      f32x4 v0 = *(const f32x4*)(uw + off);
      f32x4 v1 = *(const f32x4*)(uw + off + 4);
      s16x8 o;
#pragma unroll
      for (int j = 0; j < 4; ++j) { o[j] = f2bf(v0[j]); o[j + 4] = f2bf(v1[j]); }
      *(s16x8*)(wsbf + tid * 8) = o;
    }
  } else {
    // stats: 4 threads per n, each sums 256 k's
    const int t = threadIdx.x;
    const int n = t >> 2, p = t & 3;
    const float* dwn = dw + n * HDIM;
    float s1 = 0.f, s2 = 0.f;
    for (int j = 0; j < 32; ++j) {
      int k = p * 256 + j * 8;
      f32x4 v0 = *(const f32x4*)(dwn + k);
      f32x4 v1 = *(const f32x4*)(dwn + k + 4);
      f32x4 g0 = *(const f32x4*)(nw + k);
      f32x4 g1 = *(const f32x4*)(nw + k + 4);
      f32x4 b0 = *(const f32x4*)(nb + k);
      f32x4 b1 = *(const f32x4*)(nb + k + 4);
#pragma unroll
      for (int jj = 0; jj < 4; ++jj) {
        s1 += bf2f(f2bf(v0[jj] * g0[jj])) + bf2f(f2bf(v1[jj] * g1[jj]));
        s2 += v0[jj] * b0[jj] + v1[jj] * b1[jj];
      }
    }
    s1 += __shfl_xor(s1, 1); s1 += __shfl_xor(s1, 2);
    s2 += __shfl_xor(s2, 1); s2 += __shfl_xor(s2, 2);
    if (p == 0) {
      g_wstat[n]      = s1;            // sdw
      g_wstat[64 + n] = db[n] + s2;    // db2
    }
  }
}

extern "C" __global__ __launch_bounds__(256, 4)
void adapter_fused(const float* __restrict__ x,
                   const float* __restrict__ ub,
                   const short* __restrict__ dwb,
                   const short* __restrict__ uwb,
                   float* __restrict__ out)
{
  // x-tile bf16, row stride exactly 2048 B; 16B slots XOR-swizzled by (row&7)
  // so fragment reads (16 rows at same k-slot) spread over 8 bank-groups.
  __shared__ __align__(16) short xbf[16 * 1024];     // 32 KB
  __shared__ float muL[16];
  __shared__ float rsL[16];
  __shared__ __align__(16) short g[16][72];          // 2.3 KB

  const int t    = threadIdx.x;
  const int w    = t >> 6;            // wave 0..3
  const int lane = t & 63;
  const int q    = lane >> 4;
  const int c    = lane & 15;
  const size_t rowbase = (size_t)blockIdx.x * 16;

  // ---- phase 1: coalesced x load, 16-deep staging, stats, bf16 -> swizzled LDS ----
  {
    const int r  = t >> 4;            // row 0..15 (one row per 16 threads, same wave)
    const int c2 = t & 15;
    const float* xrow = x + (rowbase + r) * HDIM;

    f32x4 v[16];                      // issue ALL 16 loads: 16 KB in flight per wave
#pragma unroll
    for (int i = 0; i < 16; ++i) v[i] = ((const f32x4*)xrow)[i * 16 + c2];

    float sum = 0.f, ssq = 0.f;
#pragma unroll
    for (int i = 0; i < 16; ++i) {
      s16x4 o;
#pragma unroll
      for (int k = 0; k < 4; ++k) {
        float f = v[i][k]; sum += f; ssq += f * f; o[k] = f2bf(f);
      }
      // byte-in-row = (float col)*2 = i*128 + c2*8 ; swizzle flips bits 4..6
      int b = (i * 128 + c2 * 8) ^ ((r & 7) << 4);
      *(s16x4*)((char*)xbf + r * 2048 + b) = o;
    }
#pragma unroll
    for (int m = 1; m < 16; m <<= 1) {
      sum += __shfl_xor(sum, m);
      ssq += __shfl_xor(ssq, m);
    }
    if (c2 == 0) {
      float mu = sum * (1.0f / HDIM);
      muL[r] = mu;
      rsL[r] = rsqrtf(ssq * (1.0f / HDIM) - mu * mu + 1e-5f);
    }
  }
  __syncthreads();

  // ---- phase 2: down-GEMM, wave w owns n-block [w*16,(w+1)*16); A from LDS ----
  {
    const short* pB = dwb + (size_t)(w * 16 + c) * HDIM + q * 8;   // B[k][n]=dw'[n][k]
    const char*  arow = (const char*)xbf + c * 2048;
    const int    sw   = (c & 7) << 4;
    f32x4 acc = {0.f, 0.f, 0.f, 0.f};
#pragma unroll 8
    for (int ks = 0; ks < 32; ++ks) {
      s16x8 a = *(const s16x8*)(arow + ((ks * 64 + q * 16) ^ sw));
      s16x8 b = *(const s16x8*)(pB + ks * 32);
      acc = __builtin_amdgcn_mfma_f32_16x16x32_bf16(a, b, acc, 0, 0, 0);
    }

    const float sdw = g_wstat[w * 16 + c];
    const float dbv = g_wstat[64 + w * 16 + c];
#pragma unroll
    for (int i = 0; i < 4; ++i) {
      const int m = q * 4 + i;                       // D row (uniform across c-lanes)
      float h = rsL[m] * (acc[i] - muL[m] * sdw) + dbv;
      g[m][w * 16 + c] = f2bf(0.5f * h * (1.0f + erff(h * 0.70710678118654752f)));
    }
  }
  __syncthreads();

  // ---- phase 3: up-GEMM, wave w owns cols [w*256,(w+1)*256) ----
  const s16x8 a0 = *(const s16x8*)&g[c][q * 8];       // k = 0..31
  const s16x8 a1 = *(const s16x8*)&g[c][32 + q * 8];  // k = 32..63

  const float* xr0 = x + (rowbase + q * 4 + 0) * HDIM + w * 256 + c;
  const float* xr1 = x + (rowbase + q * 4 + 1) * HDIM + w * 256 + c;
  const float* xr2 = x + (rowbase + q * 4 + 2) * HDIM + w * 256 + c;
  const float* xr3 = x + (rowbase + q * 4 + 3) * HDIM + w * 256 + c;
  float* or0 = out + (rowbase + q * 4 + 0) * HDIM + w * 256 + c;
  float* or1 = out + (rowbase + q * 4 + 1) * HDIM + w * 256 + c;
  float* or2 = out + (rowbase + q * 4 + 2) * HDIM + w * 256 + c;
  float* or3 = out + (rowbase + q * 4 + 3) * HDIM + w * 256 + c;
  const short* pu  = uwb + (size_t)(w * 256 + c) * BDIM + q * 8;
  const float* pub = ub + w * 256 + c;

#pragma unroll 4
  for (int nt = 0; nt < 16; ++nt) {
    const short* uwrow = pu + (size_t)nt * 16 * BDIM;
    s16x8 b0 = *(const s16x8*)(uwrow);
    s16x8 b1 = *(const s16x8*)(uwrow + 32);
    f32x4 o4 = {0.f, 0.f, 0.f, 0.f};
    o4 = __builtin_amdgcn_mfma_f32_16x16x32_bf16(a0, b0, o4, 0, 0, 0);
    o4 = __builtin_amdgcn_mfma_f32_16x16x32_bf16(a1, b1, o4, 0, 0, 0);
    const float ubv = pub[nt * 16];
    const int co = nt * 16;                            // imm-offset loads/stores
    or0[co] = o4[0] + ubv + xr0[co];                   // residual from fp32 x (L3-hot)
    or1[co] = o4[1] + ubv + xr1[co];
    or2[co] = o4[2] + ubv + xr2[co];
    or3[co] = o4[3] + ubv + xr3[co];
  }
}

extern "C" void kernel_launch(void* const* d_in, const int* in_sizes, int n_in,
                              void* d_out, int out_size, void* d_ws, size_t ws_size,
                              hipStream_t stream) {
  const float* x  = (const float*)d_in[0];
  const float* nw = (const float*)d_in[1];
  const float* nb = (const float*)d_in[2];
  const float* dw = (const float*)d_in[3];
  const float* db = (const float*)d_in[4];
  const float* uw = (const float*)d_in[5];
  const float* ub = (const float*)d_in[6];
  float* out = (float*)d_out;

  short* wsbf = (short*)d_ws;                         // exactly 256 KB bf16 weights
  prep_weights<<<65, 256, 0, stream>>>(dw, uw, nw, nb, db, wsbf);

  const int rows = in_sizes[0] / HDIM;                // 32768
  const int grid = rows / 16;                         // 2048 blocks x 4 waves
  adapter_fused<<<grid, 256, 0, stream>>>(x, ub, wsbf, wsbf + 65536, out);
}

// Round 5
// 299.263 us; speedup vs baseline: 1.0643x; 1.0006x over previous
//
#include <hip/hip_runtime.h>

// Fused ResidualTokenAdapter v5: async-DMA ingest (global_load_lds).
// LN folded into down-proj (h_n = rs*(dot(x_raw,dw'_n) - mu*sdw_n) + db'_n).
// Rounds 2-4 lesson: hipcc register-minimizes every staging scheme (VGPR 40-52),
// leaving ~2-4 loads in flight/wave -> ~2.2 TB/s latency wall regardless of
// occupancy/structure. v5 ingests x via __builtin_amdgcn_global_load_lds width=16:
// 64 x 1KB DMA chunks per block issued up front (zero VGPR cost), fp32 tile in LDS
// (row stride 4112B -> 2-way-free fragment reads), bf16 convert in-VALU during the
// down-GEMM, residual served from the same LDS tile (no L3 re-read).
// Block = 512 thr (8 waves), 16 rows. Phase1: waves = Khalf x Nquarter partials;
// phase2: 4 waves reduce+GELU; phase3: 8 waves x 128-col up-GEMM + store.
// LDS 76.8 KB -> 2 blocks/CU = 16 waves/CU.

#define HDIM  1024
#define BDIM  64
#define XROWB 4112   // fp32 x-tile row stride in bytes (4096 + 16) -> bank shift 4/row

using s16x8 = __attribute__((ext_vector_type(8))) short;
using f32x4 = __attribute__((ext_vector_type(4))) float;

__device__ float g_wstat[128];   // [0:64) sdw, [64:128) db2

__device__ __forceinline__ short f2bf(float f) {
  unsigned u = __builtin_bit_cast(unsigned, f);
  u += 0x7fffu + ((u >> 16) & 1u);          // round-to-nearest-even
  return (short)(u >> 16);
}
__device__ __forceinline__ float bf2f(short s) {
  unsigned u = ((unsigned)(unsigned short)s) << 16;
  return __builtin_bit_cast(float, u);
}

// async 16B/lane global->LDS DMA. LDS dest = wave-uniform base + lane*16;
// global src is per-lane. C-style casts for addrspace (the only form that compiles).
__device__ __forceinline__ void gload16(const void* g, void* l) {
  __builtin_amdgcn_global_load_lds(
      (const __attribute__((address_space(1))) void*)g,
      (__attribute__((address_space(3))) void*)l,
      16, 0, 0);
}

// prep: blocks 0..63 convert weights to bf16 (gamma folded into dw);
// block 64 computes sdw[64] (bf16-rounded, matching GEMM operand) and db2[64].
extern "C" __global__ void prep_weights(const float* __restrict__ dw,
                                        const float* __restrict__ uw,
                                        const float* __restrict__ nw,
                                        const float* __restrict__ nb,
                                        const float* __restrict__ db,
                                        short* __restrict__ wsbf) {
  const int b = blockIdx.x;
  if (b < 64) {
    int tid = b * 256 + threadIdx.x;                 // 0..16383
    if (tid < 8192) {                                // dw' = gamma * dw
      int off = tid * 8;
      int k = off & (HDIM - 1);
      f32x4 v0 = *(const f32x4*)(dw + off);
      f32x4 v1 = *(const f32x4*)(dw + off + 4);
      f32x4 g0 = *(const f32x4*)(nw + k);
      f32x4 g1 = *(const f32x4*)(nw + k + 4);
      s16x8 o;
#pragma unroll
      for (int j = 0; j < 4; ++j) {
        o[j]     = f2bf(v0[j] * g0[j]);
        o[j + 4] = f2bf(v1[j] * g1[j]);
      }
      *(s16x8*)(wsbf + tid * 8) = o;
    } else {                                         // uw unchanged
      int off = (tid - 8192) * 8;
      f32x4 v0 = *(const f32x4*)(uw + off);
      f32x4 v1 = *(const f32x4*)(uw + off + 4);
      s16x8 o;
#pragma unroll
      for (int j = 0; j < 4; ++j) { o[j] = f2bf(v0[j]); o[j + 4] = f2bf(v1[j]); }
      *(s16x8*)(wsbf + tid * 8) = o;
    }
  } else {
    // stats: 4 threads per n, each sums 256 k's
    const int t = threadIdx.x;
    const int n = t >> 2, p = t & 3;
    const float* dwn = dw + n * HDIM;
    float s1 = 0.f, s2 = 0.f;
    for (int j = 0; j < 32; ++j) {
      int k = p * 256 + j * 8;
      f32x4 v0 = *(const f32x4*)(dwn + k);
      f32x4 v1 = *(const f32x4*)(dwn + k + 4);
      f32x4 g0 = *(const f32x4*)(nw + k);
      f32x4 g1 = *(const f32x4*)(nw + k + 4);
      f32x4 b0 = *(const f32x4*)(nb + k);
      f32x4 b1 = *(const f32x4*)(nb + k + 4);
#pragma unroll
      for (int jj = 0; jj < 4; ++jj) {
        s1 += bf2f(f2bf(v0[jj] * g0[jj])) + bf2f(f2bf(v1[jj] * g1[jj]));
        s2 += v0[jj] * b0[jj] + v1[jj] * b1[jj];
      }
    }
    s1 += __shfl_xor(s1, 1); s1 += __shfl_xor(s1, 2);
    s2 += __shfl_xor(s2, 1); s2 += __shfl_xor(s2, 2);
    if (p == 0) {
      g_wstat[n]      = s1;            // sdw
      g_wstat[64 + n] = db[n] + s2;    // db2
    }
  }
}

extern "C" __global__ __launch_bounds__(512, 4)
void adapter_fused(const float* __restrict__ x,
                   const float* __restrict__ ub,
                   const short* __restrict__ dwb,
                   const short* __restrict__ uwb,
                   float* __restrict__ out)
{
  __shared__ __align__(16) char  xf[16 * XROWB];     // fp32 x-tile (DMA dest), 65792 B
  __shared__ __align__(16) float part[2][64][20];    // K-half partials, 10240 B
  __shared__ __align__(16) short g[16][72];          // gelu(h) bf16, 2304 B
  __shared__ float shalf[2][16];                     // per-K-half row sums
  __shared__ float qhalf[2][16];                     // per-K-half row sumsq

  const int t    = threadIdx.x;
  const int w    = t >> 6;            // wave 0..7
  const int lane = t & 63;
  const int q    = lane >> 4;
  const int c    = lane & 15;
  const size_t rowbase = (size_t)blockIdx.x * 16;

  // ---- phase 0: DMA the 16x1024 fp32 x-tile into LDS (64 x 1KB chunks) ----
  // chunk ch: row = ch>>2, quarter = ch&3; zero VGPR cost, 8 in flight per wave.
  {
    const char* gx = (const char*)(x + rowbase * HDIM);
#pragma unroll
    for (int i = 0; i < 8; ++i) {
      const int ch = w * 8 + i;
      gload16(gx + ch * 1024 + lane * 16,
              xf + (ch >> 2) * XROWB + (ch & 3) * 1024);
    }
  }
  __syncthreads();   // compiler emits s_waitcnt vmcnt(0) before s_barrier: tile resident

  // ---- phase 1: partial down-GEMM; wave = (kh = w>>2, nw = w&3) ----
  // lane(q,c): A row c, K-half kh, q-interleaved fragments; bf16 convert in-VALU;
  // stats accumulated from the same fp32 values.
  {
    const int kh = w >> 2, nw = w & 3;
    const char*  arow = xf + c * XROWB + kh * 2048;
    const short* pB   = dwb + (size_t)(nw * 16 + c) * HDIM + kh * 512 + q * 8;
    f32x4 acc = {0.f, 0.f, 0.f, 0.f};
    float sum = 0.f, ssq = 0.f;
#pragma unroll
    for (int ks = 0; ks < 16; ++ks) {
      f32x4 u0 = *(const f32x4*)(arow + ks * 128 + q * 32);
      f32x4 u1 = *(const f32x4*)(arow + ks * 128 + q * 32 + 16);
      s16x8 b = *(const s16x8*)(pB + ks * 32);
      s16x8 a;
#pragma unroll
      for (int j = 0; j < 4; ++j) {
        float f0 = u0[j]; sum += f0; ssq += f0 * f0; a[j]     = f2bf(f0);
        float f1 = u1[j]; sum += f1; ssq += f1 * f1; a[j + 4] = f2bf(f1);
      }
      acc = __builtin_amdgcn_mfma_f32_16x16x32_bf16(a, b, acc, 0, 0, 0);
    }
    // half-row stats for row c (4 q-lanes jointly saw all 512 elems of the half)
    sum += __shfl_xor(sum, 16); sum += __shfl_xor(sum, 32);
    ssq += __shfl_xor(ssq, 16); ssq += __shfl_xor(ssq, 32);
    if (nw == 0 && lane < 16) { shalf[kh][c] = sum; qhalf[kh][c] = ssq; }
    *(f32x4*)&part[kh][nw * 16 + c][q * 4] = acc;    // D[q*4+i][n=nw*16+c]
  }
  __syncthreads();

  // ---- phase 2: waves 0..3 reduce K-halves, LN-correct, GELU -> g ----
  if (w < 4) {
    const int n = w * 16 + c;
    f32x4 p0 = *(const f32x4*)&part[0][n][q * 4];
    f32x4 p1 = *(const f32x4*)&part[1][n][q * 4];
    f32x4 h4 = p0 + p1;
    float sT = shalf[0][c] + shalf[1][c];            // stats for row c
    float qT = qhalf[0][c] + qhalf[1][c];
    float muv = sT * (1.0f / HDIM);
    float rsv = rsqrtf(qT * (1.0f / HDIM) - muv * muv + 1e-5f);
    const float sdw = g_wstat[n];
    const float dbv = g_wstat[64 + n];
#pragma unroll
    for (int i = 0; i < 4; ++i) {
      const float m  = __shfl(muv, q * 4 + i);       // row q*4+i stats live in lane q*4+i
      const float rv = __shfl(rsv, q * 4 + i);
      float h = rv * (h4[i] - m * sdw) + dbv;
      g[q * 4 + i][n] = f2bf(0.5f * h * (1.0f + erff(h * 0.70710678118654752f)));
    }
  }
  __syncthreads();

  // ---- phase 3: up-GEMM; wave w owns cols [w*128,(w+1)*128); residual from LDS ----
  {
    const s16x8 a0 = *(const s16x8*)&g[c][q * 8];       // k = 0..31
    const s16x8 a1 = *(const s16x8*)&g[c][32 + q * 8];  // k = 32..63
    const short* pu = uwb + (size_t)(w * 128 + c) * BDIM + q * 8;
    float* ob = out + rowbase * HDIM + w * 128 + c;
#pragma unroll 2
    for (int nt = 0; nt < 8; ++nt) {
      const short* uwrow = pu + (size_t)nt * 16 * BDIM;
      s16x8 b0 = *(const s16x8*)(uwrow);
      s16x8 b1 = *(const s16x8*)(uwrow + 32);
      f32x4 o4 = {0.f, 0.f, 0.f, 0.f};
      o4 = __builtin_amdgcn_mfma_f32_16x16x32_bf16(a0, b0, o4, 0, 0, 0);
      o4 = __builtin_amdgcn_mfma_f32_16x16x32_bf16(a1, b1, o4, 0, 0, 0);
      const int nc = w * 128 + nt * 16 + c;
      const float ubv = ub[nc];
#pragma unroll
      for (int i = 0; i < 4; ++i) {
        const int m = q * 4 + i;
        float res = *(const float*)(xf + m * XROWB + nc * 4);  // fp32 x from LDS
        ob[(size_t)m * HDIM + nt * 16] = o4[i] + ubv + res;
      }
    }
  }
}

extern "C" void kernel_launch(void* const* d_in, const int* in_sizes, int n_in,
                              void* d_out, int out_size, void* d_ws, size_t ws_size,
                              hipStream_t stream) {
  const float* x  = (const float*)d_in[0];
  const float* nw = (const float*)d_in[1];
  const float* nb = (const float*)d_in[2];
  const float* dw = (const float*)d_in[3];
  const float* db = (const float*)d_in[4];
  const float* uw = (const float*)d_in[5];
  const float* ub = (const float*)d_in[6];
  float* out = (float*)d_out;

  short* wsbf = (short*)d_ws;                         // exactly 256 KB bf16 weights
  prep_weights<<<65, 256, 0, stream>>>(dw, uw, nw, nb, db, wsbf);

  const int rows = in_sizes[0] / HDIM;                // 32768
  const int grid = rows / 16;                         // 2048 blocks x 8 waves
  adapter_fused<<<grid, 512, 0, stream>>>(x, ub, wsbf, wsbf + 65536, out);
}

// Round 6
// 281.966 us; speedup vs baseline: 1.1295x; 1.0613x over previous
//
#include <hip/hip_runtime.h>

// Fused ResidualTokenAdapter v6: persistent blocks + cross-tile double-buffered DMA.
// LN folded into down-proj (h_n = rs*(dot(x_raw,dw'_n) - mu*sdw_n) + db'_n).
// Rounds 0-5 lesson: every bulk-synchronous one-tile-per-block variant lands at
// time ~= bytes / 2TB/s regardless of structure: the chip-wide memory duty cycle
// is ~30% (DMA burst -> full drain -> compute -> exit). v6 applies T3/T4 ACROSS
// tiles: 256 persistent blocks (1/CU, 16 waves) x 8 tiles, two LDS x-buffers,
// DMA(t+1) in flight during compute(t), counted s_waitcnt vmcnt(20/16) (never 0
// in-loop), raw s_barrier (no drain). Both GEMM B matrices hoisted to registers
// (tile-invariant) so steady-state VMEM = 4 DMA + 16 stores per wave per tile.
// LDS: 2x64.25KB x-tiles + part 20KB + g 2.3KB + stats 0.5KB = 151KB -> 1 block/CU.

#define HDIM  1024
#define BDIM  64
#define XROWB 4112   // x-tile row stride bytes (4096+16): bank shift 4/row, 2-way free
#define TILES 8

using s16x8 = __attribute__((ext_vector_type(8))) short;
using f32x4 = __attribute__((ext_vector_type(4))) float;

__device__ float g_wstat[128];   // [0:64) sdw, [64:128) db2

__device__ __forceinline__ short f2bf(float f) {
  unsigned u = __builtin_bit_cast(unsigned, f);
  u += 0x7fffu + ((u >> 16) & 1u);          // round-to-nearest-even
  return (short)(u >> 16);
}
__device__ __forceinline__ float bf2f(short s) {
  unsigned u = ((unsigned)(unsigned short)s) << 16;
  return __builtin_bit_cast(float, u);
}

// async 16B/lane global->LDS DMA; LDS dest wave-uniform, global src per-lane.
__device__ __forceinline__ void gload16(const void* g, void* l) {
  __builtin_amdgcn_global_load_lds(
      (const __attribute__((address_space(1))) void*)g,
      (__attribute__((address_space(3))) void*)l,
      16, 0, 0);
}

// prep: blocks 0..63 convert weights to bf16 (gamma folded into dw);
// block 64 computes sdw[64] (bf16-rounded, matching GEMM operand) and db2[64].
extern "C" __global__ void prep_weights(const float* __restrict__ dw,
                                        const float* __restrict__ uw,
                                        const float* __restrict__ nw,
                                        const float* __restrict__ nb,
                                        const float* __restrict__ db,
                                        short* __restrict__ wsbf) {
  const int b = blockIdx.x;
  if (b < 64) {
    int tid = b * 256 + threadIdx.x;                 // 0..16383
    if (tid < 8192) {                                // dw' = gamma * dw
      int off = tid * 8;
      int k = off & (HDIM - 1);
      f32x4 v0 = *(const f32x4*)(dw + off);
      f32x4 v1 = *(const f32x4*)(dw + off + 4);
      f32x4 g0 = *(const f32x4*)(nw + k);
      f32x4 g1 = *(const f32x4*)(nw + k + 4);
      s16x8 o;
#pragma unroll
      for (int j = 0; j < 4; ++j) {
        o[j]     = f2bf(v0[j] * g0[j]);
        o[j + 4] = f2bf(v1[j] * g1[j]);
      }
      *(s16x8*)(wsbf + tid * 8) = o;
    } else {                                         // uw unchanged
      int off = (tid - 8192) * 8;
      f32x4 v0 = *(const f32x4*)(uw + off);
      f32x4 v1 = *(const f32x4*)(uw + off + 4);
      s16x8 o;
#pragma unroll
      for (int j = 0; j < 4; ++j) { o[j] = f2bf(v0[j]); o[j + 4] = f2bf(v1[j]); }
      *(s16x8*)(wsbf + tid * 8) = o;
    }
  } else {
    // stats: 4 threads per n, each sums 256 k's
    const int t = threadIdx.x;
    const int n = t >> 2, p = t & 3;
    const float* dwn = dw + n * HDIM;
    float s1 = 0.f, s2 = 0.f;
    for (int j = 0; j < 32; ++j) {
      int k = p * 256 + j * 8;
      f32x4 v0 = *(const f32x4*)(dwn + k);
      f32x4 v1 = *(const f32x4*)(dwn + k + 4);
      f32x4 g0 = *(const f32x4*)(nw + k);
      f32x4 g1 = *(const f32x4*)(nw + k + 4);
      f32x4 b0 = *(const f32x4*)(nb + k);
      f32x4 b1 = *(const f32x4*)(nb + k + 4);
#pragma unroll
      for (int jj = 0; jj < 4; ++jj) {
        s1 += bf2f(f2bf(v0[jj] * g0[jj])) + bf2f(f2bf(v1[jj] * g1[jj]));
        s2 += v0[jj] * b0[jj] + v1[jj] * b1[jj];
      }
    }
    s1 += __shfl_xor(s1, 1); s1 += __shfl_xor(s1, 2);
    s2 += __shfl_xor(s2, 1); s2 += __shfl_xor(s2, 2);
    if (p == 0) {
      g_wstat[n]      = s1;            // sdw
      g_wstat[64 + n] = db[n] + s2;    // db2
    }
  }
}

extern "C" __global__ __launch_bounds__(1024, 4)
void adapter_fused(const float* __restrict__ x,
                   const float* __restrict__ ub,
                   const short* __restrict__ dwb,
                   const short* __restrict__ uwb,
                   float* __restrict__ out)
{
  __shared__ __align__(16) char  xfa[16 * XROWB];    // 65792 B, x-tile buffer A
  __shared__ __align__(16) char  xfb[16 * XROWB];    // 65792 B, x-tile buffer B
  __shared__ __align__(16) float part[4][64][20];    // K-quarter partials, 20480 B
  __shared__ __align__(16) short g[16][72];          // gelu(h) bf16, 2304 B
  __shared__ float ssumS[4][16];                     // per-quarter row sums
  __shared__ float sssqS[4][16];                     // per-quarter row sumsq

  const int tid  = threadIdx.x;
  const int w    = tid >> 6;          // wave 0..15
  const int lane = tid & 63;
  const int q    = lane >> 4;
  const int c    = lane & 15;
  const int kh   = w >> 2;            // K-quarter (phase 1)
  const int nw   = w & 3;             // n-block   (phase 1)
  const size_t baserow = (size_t)blockIdx.x * (TILES * 16);

  // ---- hoist tile-invariant weights into registers (static-indexed, unrolled) ----
  s16x8 bf[8];                        // down B frags: wave (kh,nw), ks=0..7
  {
    const short* pB = dwb + (size_t)(nw * 16 + c) * HDIM + kh * 256 + q * 8;
#pragma unroll
    for (int ks = 0; ks < 8; ++ks) bf[ks] = *(const s16x8*)(pB + ks * 32);
  }
  s16x8 u0f[4], u1f[4]; float ubv[4]; // up B frags + bias: wave owns cols [w*64,(w+1)*64)
  {
    const short* pu = uwb + (size_t)(w * 64 + c) * BDIM + q * 8;
#pragma unroll
    for (int nt = 0; nt < 4; ++nt) {
      u0f[nt] = *(const s16x8*)(pu + (size_t)nt * 16 * BDIM);
      u1f[nt] = *(const s16x8*)(pu + (size_t)nt * 16 * BDIM + 32);
      ubv[nt] = ub[w * 64 + nt * 16 + c];
    }
  }
  float sdw = 0.f, dbv = 0.f;
  if (w < 4) { sdw = g_wstat[w * 16 + c]; dbv = g_wstat[64 + w * 16 + c]; }

  // wave w DMAs global row (tile,w) -> its LDS row (4 x 1KB chunks, dest uniform)
  char* cur = xfa;
  char* nxt = xfb;
  auto dma_tile = [&](int tt, char* dst) {
    const char* gx = (const char*)(x + (baserow + (size_t)tt * 16 + w) * HDIM);
    char* ld = dst + w * XROWB;
#pragma unroll
    for (int i = 0; i < 4; ++i)
      gload16(gx + i * 1024 + lane * 16, ld + i * 1024);
  };

  // ---- prologue: tiles 0 and 1 in flight; wait own tile-0 chunks; barrier ----
  dma_tile(0, xfa);
  dma_tile(1, xfb);
  asm volatile("s_waitcnt vmcnt(4)" ::: "memory");   // own tile-0 arrived (tile-1 outstanding)
  __builtin_amdgcn_s_barrier();                      // all waves' tile-0 resident
  __builtin_amdgcn_sched_barrier(0);

  for (int t = 0; t < TILES; ++t) {
    const size_t trow = baserow + (size_t)t * 16;

    // ---- phase 1: partial down-GEMM, wave (kh,nw); A from cur, B from regs ----
    {
      const char* arow = cur + c * XROWB + kh * 1024;
      f32x4 acc = {0.f, 0.f, 0.f, 0.f};
      float sum = 0.f, ssq = 0.f;
#pragma unroll
      for (int ks = 0; ks < 8; ++ks) {
        f32x4 u0 = *(const f32x4*)(arow + ks * 128 + q * 32);
        f32x4 u1 = *(const f32x4*)(arow + ks * 128 + q * 32 + 16);
        s16x8 a;
#pragma unroll
        for (int j = 0; j < 4; ++j) {
          float f0 = u0[j]; sum += f0; ssq += f0 * f0; a[j]     = f2bf(f0);
          float f1 = u1[j]; sum += f1; ssq += f1 * f1; a[j + 4] = f2bf(f1);
        }
        acc = __builtin_amdgcn_mfma_f32_16x16x32_bf16(a, bf[ks], acc, 0, 0, 0);
      }
      sum += __shfl_xor(sum, 16); sum += __shfl_xor(sum, 32);
      ssq += __shfl_xor(ssq, 16); ssq += __shfl_xor(ssq, 32);
      if (nw == 0 && lane < 16) { ssumS[kh][c] = sum; sssqS[kh][c] = ssq; }
      *(f32x4*)&part[kh][nw * 16 + c][q * 4] = acc;  // D[q*4+i][n=nw*16+c]
    }
    asm volatile("s_waitcnt lgkmcnt(0)" ::: "memory");
    __builtin_amdgcn_s_barrier();                    // B1: partials/stats ready
    __builtin_amdgcn_sched_barrier(0);

    // ---- phase 2: waves 0..3 reduce quarters, LN-correct, GELU -> g ----
    if (w < 4) {
      const int n = w * 16 + c;
      f32x4 h4 = *(const f32x4*)&part[0][n][q * 4];
      h4 += *(const f32x4*)&part[1][n][q * 4];
      h4 += *(const f32x4*)&part[2][n][q * 4];
      h4 += *(const f32x4*)&part[3][n][q * 4];
      float sT = (ssumS[0][c] + ssumS[1][c]) + (ssumS[2][c] + ssumS[3][c]);
      float qT = (sssqS[0][c] + sssqS[1][c]) + (sssqS[2][c] + sssqS[3][c]);
      float muv = sT * (1.0f / HDIM);
      float rsv = rsqrtf(qT * (1.0f / HDIM) - muv * muv + 1e-5f);
#pragma unroll
      for (int i = 0; i < 4; ++i) {
        const float m  = __shfl(muv, q * 4 + i);     // row q*4+i stats live in lane q*4+i
        const float rv = __shfl(rsv, q * 4 + i);
        float h = rv * (h4[i] - m * sdw) + dbv;
        g[q * 4 + i][n] = f2bf(0.5f * h * (1.0f + erff(h * 0.70710678118654752f)));
      }
    }
    asm volatile("s_waitcnt lgkmcnt(0)" ::: "memory");
    __builtin_amdgcn_s_barrier();                    // B2: g ready
    __builtin_amdgcn_sched_barrier(0);

    // ---- phase 3: up-GEMM, wave w cols [w*64,(w+1)*64); residual from cur ----
    {
      const s16x8 a0 = *(const s16x8*)&g[c][q * 8];       // k = 0..31
      const s16x8 a1 = *(const s16x8*)&g[c][32 + q * 8];  // k = 32..63
      float* ob = out + trow * HDIM;
#pragma unroll
      for (int nt = 0; nt < 4; ++nt) {
        f32x4 o4 = {0.f, 0.f, 0.f, 0.f};
        o4 = __builtin_amdgcn_mfma_f32_16x16x32_bf16(a0, u0f[nt], o4, 0, 0, 0);
        o4 = __builtin_amdgcn_mfma_f32_16x16x32_bf16(a1, u1f[nt], o4, 0, 0, 0);
        const int ncol = w * 64 + nt * 16 + c;
#pragma unroll
        for (int i = 0; i < 4; ++i) {
          const int m = q * 4 + i;
          float res = *(const float*)(cur + m * XROWB + ncol * 4);
          ob[(size_t)m * HDIM + ncol] = o4[i] + ubv[nt] + res;
        }
      }
    }

    if (t + 1 < TILES) {
      asm volatile("s_waitcnt lgkmcnt(0)" ::: "memory");
      __builtin_amdgcn_s_barrier();                  // B3: cur fully consumed by all
      __builtin_amdgcn_sched_barrier(0);             // pin DMA issue after barrier
      if (t + 2 < TILES) {
        dma_tile(t + 2, cur);                        // refill the consumed buffer
        // outstanding (old->new): DMA(t+1)x4, stores(t)x16, DMA(t+2)x4 = 24
        asm volatile("s_waitcnt vmcnt(20)" ::: "memory");   // retire DMA(t+1) only
      } else {
        // outstanding: DMA(t+1)x4, stores(t)x16 = 20 -> retire DMA(t+1)
        asm volatile("s_waitcnt vmcnt(16)" ::: "memory");
      }
      __builtin_amdgcn_s_barrier();                  // B4: tile t+1 resident for all
      __builtin_amdgcn_sched_barrier(0);
      char* tmp = cur; cur = nxt; nxt = tmp;
    }
  }
}

extern "C" void kernel_launch(void* const* d_in, const int* in_sizes, int n_in,
                              void* d_out, int out_size, void* d_ws, size_t ws_size,
                              hipStream_t stream) {
  const float* x  = (const float*)d_in[0];
  const float* nw = (const float*)d_in[1];
  const float* nb = (const float*)d_in[2];
  const float* dw = (const float*)d_in[3];
  const float* db = (const float*)d_in[4];
  const float* uw = (const float*)d_in[5];
  const float* ub = (const float*)d_in[6];
  float* out = (float*)d_out;

  short* wsbf = (short*)d_ws;                         // exactly 256 KB bf16 weights
  prep_weights<<<65, 256, 0, stream>>>(dw, uw, nw, nb, db, wsbf);

  const int rows = in_sizes[0] / HDIM;                // 32768
  const int grid = rows / (16 * TILES);               // 256 persistent blocks (1/CU)
  adapter_fused<<<grid, 1024, 0, stream>>>(x, ub, wsbf, wsbf + 65536, out);
}